// Round 1
// baseline (760.977 us; speedup 1.0000x reference)
//
#include <hip/hip_runtime.h>

typedef __attribute__((ext_vector_type(4))) float float4v;
typedef __attribute__((ext_vector_type(8))) short short8;

#define NEVT 8192
#define NSEVT 16384
#define DIM 128
#define BM 16
#define BK 128
#define NTILE (NSEVT / BK)  // 128

__device__ __forceinline__ unsigned f2bf(float f) {
  unsigned u = __builtin_bit_cast(unsigned, f);
  return (u + 0x7FFFu + ((u >> 16) & 1u)) >> 16;  // RNE to bf16
}

// ---- kernel 1: e_proj / s_proj (wave per row, 128-dot + shuffle reduce) ----
__global__ void proj_kernel(const float* __restrict__ event,
                            const float* __restrict__ subevent,
                            const float* __restrict__ attn_w,
                            float* __restrict__ eproj,
                            float* __restrict__ sproj) {
  int gw = (int)((blockIdx.x * blockDim.x + threadIdx.x) >> 6);
  int lane = threadIdx.x & 63;
  const float* row;
  const float* w;
  float* outp;
  if (gw < NEVT) {
    row = event + (size_t)gw * DIM;
    w = attn_w + DIM;  // a_e
    outp = eproj + gw;
  } else {
    row = subevent + (size_t)(gw - NEVT) * DIM;
    w = attn_w;  // a_s
    outp = sproj + (gw - NEVT);
  }
  float2 x = *(const float2*)(row + lane * 2);
  float2 ww = *(const float2*)(w + lane * 2);
  float p = x.x * ww.x + x.y * ww.y;
#pragma unroll
  for (int off = 32; off > 0; off >>= 1) p += __shfl_down(p, off, 64);
  if (lane == 0) *outp = p;
}

// ---- kernel 2: subevent -> bf16 in MFMA B-fragment order ----
// frag[((kt*8 + db)*64 + lane)*8 + j] = bf16(subevent[kt*32 + (lane>>4)*8 + j][db*16 + (lane&15)])
__global__ void frag_kernel(const float* __restrict__ sub,
                            unsigned short* __restrict__ frag) {
  int tid = blockIdx.x * 256 + threadIdx.x;  // 512*8*64 = 262144 total
  int lane = tid & 63;
  int db = (tid >> 6) & 7;
  int kt = tid >> 9;
  int r0 = kt * 32 + ((lane >> 4) << 3);
  int col = db * 16 + (lane & 15);
  unsigned pk[4];
#pragma unroll
  for (int jj = 0; jj < 4; ++jj) {
    unsigned lo = f2bf(sub[(size_t)(r0 + 2 * jj) * DIM + col]);
    unsigned hi = f2bf(sub[(size_t)(r0 + 2 * jj + 1) * DIM + col]);
    pk[jj] = lo | (hi << 16);
  }
  uint4 v = {pk[0], pk[1], pk[2], pk[3]};
  *(uint4*)(frag + (size_t)tid * 8) = v;
}

// ---- kernel 3: fused streaming softmax + PV via MFMA ----
// BM=16 rows per WG, 256 threads (4 waves), each wave owns 32 of the 128 dims.
// Single pass over adj: p = exp(lrelu(adj*(e+s))), denom += p (fp32),
// P = bf16(p*adj) staged in double-buffered LDS -> mfma_f32_16x16x32_bf16.
__global__ __launch_bounds__(256, 2) void fused_kernel(
    const float* __restrict__ adj, const float* __restrict__ event,
    const unsigned short* __restrict__ subfrag, const float* __restrict__ eproj,
    const float* __restrict__ sproj, float* __restrict__ out) {
  __shared__ unsigned short P[2][BM][132];  // +4 pad: 8B-aligned rows, mild bank spread
  __shared__ float dsum[BM][32];

  const int t = threadIdx.x;
  const int lane = t & 63;
  const int wave = t >> 6;
  const int r0 = blockIdx.x * BM;
  const int rA = t >> 5;        // 0..7
  const int cL = (t & 31) * 4;  // 0..124
  const int m = lane & 15;
  const int q = lane >> 4;

  const float ep0 = eproj[r0 + rA];
  const float ep1 = eproj[r0 + rA + 8];

  const float* adj0 = adj + (size_t)(r0 + rA) * NSEVT + cL;
  const float* adj1 = adj + (size_t)(r0 + rA + 8) * NSEVT + cL;

  float4v a0 = *(const float4v*)(adj0);
  float4v a1 = *(const float4v*)(adj1);
  float4v sp = *(const float4v*)(sproj + cL);

  float4v acc0 = {0.f, 0.f, 0.f, 0.f};
  float4v acc1 = {0.f, 0.f, 0.f, 0.f};
  float d0 = 0.f, d1 = 0.f;

  for (int tile = 0; tile < NTILE; ++tile) {
    // B fragments for this tile: 4 k-steps x 2 dim-blocks (this wave's dims).
    // Issued here, consumed after the barrier (plain VGPR loads: no vmcnt
    // drain at __syncthreads, so these stay in flight).
    short8 bf[4][2];
#pragma unroll
    for (int ks = 0; ks < 4; ++ks) {
#pragma unroll
      for (int i = 0; i < 2; ++i) {
        size_t off =
            ((size_t)((tile * 4 + ks) * 8 + (wave * 2 + i)) * 64 + lane) * 8;
        bf[ks][i] = *(const short8*)(subfrag + off);
      }
    }
    // register prefetch of next adj tile (covers HBM latency across this tile)
    float4v na0 = a0, na1 = a1, nsp = sp;
    if (tile + 1 < NTILE) {
      na0 = *(const float4v*)(adj0 + (size_t)(tile + 1) * BK);
      na1 = *(const float4v*)(adj1 + (size_t)(tile + 1) * BK);
      nsp = *(const float4v*)(sproj + (tile + 1) * BK + cL);
    }
    // compute exp weights (fp32), pack p*adj to bf16
    unsigned pkA0, pkA1, pkB0, pkB1;
    {
      float w[4];
#pragma unroll
      for (int c = 0; c < 4; ++c) {
        float x = a0[c] * (ep0 + sp[c]);
        float y = fmaxf(x, 0.2f * x);  // leaky_relu(x, 0.2)
        float p = __builtin_amdgcn_exp2f(y * 1.442695040888963f);
        d0 += p;
        w[c] = p * a0[c];
      }
      pkA0 = f2bf(w[0]) | (f2bf(w[1]) << 16);
      pkA1 = f2bf(w[2]) | (f2bf(w[3]) << 16);
#pragma unroll
      for (int c = 0; c < 4; ++c) {
        float x = a1[c] * (ep1 + sp[c]);
        float y = fmaxf(x, 0.2f * x);
        float p = __builtin_amdgcn_exp2f(y * 1.442695040888963f);
        d1 += p;
        w[c] = p * a1[c];
      }
      pkB0 = f2bf(w[0]) | (f2bf(w[1]) << 16);
      pkB1 = f2bf(w[2]) | (f2bf(w[3]) << 16);
    }
    const int buf = tile & 1;
    uint2 v0 = {pkA0, pkA1};
    *(uint2*)&P[buf][rA][cL] = v0;
    uint2 v1 = {pkB0, pkB1};
    *(uint2*)&P[buf][rA + 8][cL] = v1;

    __syncthreads();  // writes(t) -> reads(t); double buffer makes 1 barrier/tile safe

#pragma unroll
    for (int ks = 0; ks < 4; ++ks) {
      const unsigned short* ap = &P[buf][m][q * 8 + ks * 32];
      uint2 lo = *(const uint2*)(ap);      // 2x b64: rows are 8B- (not 16B-) aligned
      uint2 hi = *(const uint2*)(ap + 4);
      uint4 au = {lo.x, lo.y, hi.x, hi.y};
      short8 af = __builtin_bit_cast(short8, au);
      acc0 = __builtin_amdgcn_mfma_f32_16x16x32_bf16(af, bf[ks][0], acc0, 0, 0, 0);
      acc1 = __builtin_amdgcn_mfma_f32_16x16x32_bf16(af, bf[ks][1], acc1, 0, 0, 0);
    }
    a0 = na0;
    a1 = na1;
    sp = nsp;
  }

  // denominator reduction: 32 partials per row
  dsum[rA][t & 31] = d0;
  dsum[rA + 8][t & 31] = d1;
  __syncthreads();
  if (t < BM) {
    float s = 0.f;
#pragma unroll
    for (int k = 0; k < 32; ++k) s += dsum[t][k];
    dsum[t][0] = s;
  }
  __syncthreads();

  float rd[4];
#pragma unroll
  for (int r = 0; r < 4; ++r) rd[r] = 1.0f / dsum[q * 4 + r][0];

  // C layout (16x16): col = lane&15 (dim), row = (lane>>4)*4 + reg
#pragma unroll
  for (int i = 0; i < 2; ++i) {
    int dim = wave * 32 + i * 16 + m;
#pragma unroll
    for (int r = 0; r < 4; ++r) {
      int row = r0 + q * 4 + r;
      float num = (i == 0) ? acc0[r] : acc1[r];
      out[(size_t)row * DIM + dim] =
          (event[(size_t)row * DIM + dim] + num * rd[r]) * 0.5f;
    }
  }
}

extern "C" void kernel_launch(void* const* d_in, const int* in_sizes, int n_in,
                              void* d_out, int out_size, void* d_ws,
                              size_t ws_size, hipStream_t stream) {
  const float* adj = (const float*)d_in[0];       // [8192][16384]
  const float* subevent = (const float*)d_in[1];  // [16384][128]
  const float* event = (const float*)d_in[2];     // [8192][128]
  const float* attn_w = (const float*)d_in[3];    // [256]
  float* out = (float*)d_out;                     // [8192][128] fp32

  // workspace: 4 MB bf16 B-fragments + e_proj + s_proj  (~4.3 MB total)
  unsigned short* subfrag = (unsigned short*)d_ws;
  float* eproj = (float*)((char*)d_ws + (size_t)NSEVT * DIM * 2);
  float* sproj = eproj + NEVT;

  proj_kernel<<<(NEVT + NSEVT) / 4, 256, 0, stream>>>(event, subevent, attn_w,
                                                      eproj, sproj);
  frag_kernel<<<(NSEVT / 32) * 8 * 64 / 256, 256, 0, stream>>>(subevent,
                                                               subfrag);
  fused_kernel<<<NEVT / BM, 256, 0, stream>>>(adj, event, subfrag, eproj,
                                              sproj, out);
}

// Round 2
// 735.952 us; speedup vs baseline: 1.0340x; 1.0340x over previous
//
#include <hip/hip_runtime.h>

typedef __attribute__((ext_vector_type(4))) float float4v;
typedef __attribute__((ext_vector_type(8))) short short8;

#define NEVT 8192
#define NSEVT 16384
#define DIM 128
#define BM 64
#define BK 128
#define SPLIT 4
#define CPW (NSEVT / SPLIT)  // 4096 cols per WG
#define TPW (CPW / BK)       // 32 tiles per WG

__device__ __forceinline__ unsigned f2bf(float f) {
  unsigned u = __builtin_bit_cast(unsigned, f);
  return (u + 0x7FFFu + ((u >> 16) & 1u)) >> 16;  // RNE to bf16
}

// ---- kernel 1: e_proj / s_proj (wave per row, 128-dot + shuffle reduce) ----
__global__ void proj_kernel(const float* __restrict__ event,
                            const float* __restrict__ subevent,
                            const float* __restrict__ attn_w,
                            float* __restrict__ eproj,
                            float* __restrict__ sproj) {
  int gw = (int)((blockIdx.x * blockDim.x + threadIdx.x) >> 6);
  int lane = threadIdx.x & 63;
  const float* row;
  const float* w;
  float* outp;
  if (gw < NEVT) {
    row = event + (size_t)gw * DIM;
    w = attn_w + DIM;  // a_e
    outp = eproj + gw;
  } else {
    row = subevent + (size_t)(gw - NEVT) * DIM;
    w = attn_w;  // a_s
    outp = sproj + (gw - NEVT);
  }
  float2 x = *(const float2*)(row + lane * 2);
  float2 ww = *(const float2*)(w + lane * 2);
  float p = x.x * ww.x + x.y * ww.y;
#pragma unroll
  for (int off = 32; off > 0; off >>= 1) p += __shfl_down(p, off, 64);
  if (lane == 0) *outp = p;
}

// ---- kernel 2: subevent -> bf16 in MFMA B-fragment order ----
// frag[((kt*8 + db)*64 + lane)*8 + j] =
//   bf16(subevent[kt*32 + (lane>>4)*8 + j][db*16 + (lane&15)])
__global__ void frag_kernel(const float* __restrict__ sub,
                            unsigned short* __restrict__ frag) {
  int tid = blockIdx.x * 256 + threadIdx.x;  // 262144 total
  int lane = tid & 63;
  int db = (tid >> 6) & 7;
  int kt = tid >> 9;
  int r0 = kt * 32 + ((lane >> 4) << 3);
  int col = db * 16 + (lane & 15);
  unsigned pk[4];
#pragma unroll
  for (int jj = 0; jj < 4; ++jj) {
    unsigned lo = f2bf(sub[(size_t)(r0 + 2 * jj) * DIM + col]);
    unsigned hi = f2bf(sub[(size_t)(r0 + 2 * jj + 1) * DIM + col]);
    pk[jj] = lo | (hi << 16);
  }
  uint4 v = {pk[0], pk[1], pk[2], pk[3]};
  *(uint4*)(frag + (size_t)tid * 8) = v;
}

// ---- kernel 3: fused streaming softmax + PV via MFMA (column-split) ----
// 512 blocks = 128 row-blocks (BM=64) x 4 column splits; 512 thr (8 waves).
// Each wave owns 16 of the 128 dims. Per tile: thread streams 16 adj floats
// (1 row x 16 cols), p=exp(lrelu(adj*(e+s))), P=bf16(p*adj) -> LDS (dbuf)
// -> mfma_f32_16x16x32_bf16 over 4 M-tiles. Partials to workspace.
__global__ __launch_bounds__(512, 4) void fused_kernel(
    const float* __restrict__ adj, const unsigned short* __restrict__ subfrag,
    const float* __restrict__ eproj, const float* __restrict__ sproj,
    float* __restrict__ num_ws, float* __restrict__ den_ws) {
  __shared__ unsigned short P[2][BM][132];  // +4 pad
  __shared__ float dsum[BM][8];

  const int t = threadIdx.x;
  const int lane = t & 63;
  const int wave = t >> 6;          // 0..7 = dim block
  const int mb = blockIdx.x & 127;  // row block
  const int s = blockIdx.x >> 7;    // column split
  const int r = t >> 3;             // 0..63 local row
  const int c8 = t & 7;
  const int cL = c8 * 4;
  const int row = mb * BM + r;
  const int colbase = s * CPW;

  const float ep = eproj[row];
  const float* adjp = adj + (size_t)row * NSEVT + colbase + cL;
  const float* spp = sproj + colbase + cL;

  float4v a[4], sp[4];
#pragma unroll
  for (int j = 0; j < 4; ++j) {
    a[j] = *(const float4v*)(adjp + 32 * j);
    sp[j] = *(const float4v*)(spp + 32 * j);
  }
  float4v acc[4];
#pragma unroll
  for (int mt = 0; mt < 4; ++mt) acc[mt] = (float4v){0.f, 0.f, 0.f, 0.f};
  float d = 0.f;

  const int m = lane & 15;
  const int q = lane >> 4;

  for (int tile = 0; tile < TPW; ++tile) {
    const int tg = s * TPW + tile;  // global k-tile
    // B fragments for this tile (L2/L3-resident packed subevent)
    short8 bfr[4];
#pragma unroll
    for (int ks = 0; ks < 4; ++ks) {
      size_t off = ((size_t)((tg * 4 + ks) * 8 + wave) * 64 + lane) * 8;
      bfr[ks] = *(const short8*)(subfrag + off);
    }
    // register prefetch of next adj/sproj tile (in flight across barrier)
    float4v na[4], nsp[4];
    if (tile + 1 < TPW) {
#pragma unroll
      for (int j = 0; j < 4; ++j) {
        na[j] = *(const float4v*)(adjp + (size_t)(tile + 1) * BK + 32 * j);
        nsp[j] = *(const float4v*)(spp + (tile + 1) * BK + 32 * j);
      }
    } else {
#pragma unroll
      for (int j = 0; j < 4; ++j) {
        na[j] = a[j];
        nsp[j] = sp[j];
      }
    }
    const int buf = tile & 1;
#pragma unroll
    for (int j = 0; j < 4; ++j) {
      float w[4];
#pragma unroll
      for (int c = 0; c < 4; ++c) {
        float x = a[j][c] * (ep + sp[j][c]);
        float y = fmaxf(x, 0.2f * x);  // leaky_relu 0.2
        float p = __builtin_amdgcn_exp2f(y * 1.442695040888963f);
        d += p;
        w[c] = p * a[j][c];
      }
      uint2 v = {f2bf(w[0]) | (f2bf(w[1]) << 16),
                 f2bf(w[2]) | (f2bf(w[3]) << 16)};
      *(uint2*)&P[buf][r][cL + 32 * j] = v;
    }

    __syncthreads();  // dbuf: 1 barrier/tile is race-free

#pragma unroll
    for (int ks = 0; ks < 4; ++ks) {
#pragma unroll
      for (int mt = 0; mt < 4; ++mt) {
        const unsigned short* ap = &P[buf][mt * 16 + m][ks * 32 + q * 8];
        uint2 lo = *(const uint2*)(ap);  // rows 8B-aligned (264B stride)
        uint2 hi = *(const uint2*)(ap + 4);
        uint4 au = {lo.x, lo.y, hi.x, hi.y};
        short8 af = __builtin_bit_cast(short8, au);
        acc[mt] =
            __builtin_amdgcn_mfma_f32_16x16x32_bf16(af, bfr[ks], acc[mt], 0, 0, 0);
      }
    }
#pragma unroll
    for (int j = 0; j < 4; ++j) {
      a[j] = na[j];
      sp[j] = nsp[j];
    }
  }

  // denominator partial: 8 per-thread partials per row
  dsum[r][c8] = d;
  __syncthreads();
  if (t < BM) {
    float ssum = 0.f;
#pragma unroll
    for (int k = 0; k < 8; ++k) ssum += dsum[t][k];
    den_ws[(size_t)s * NEVT + mb * BM + t] = ssum;
  }

  // numerator partials; C layout: col=lane&15 (dim), row=(lane>>4)*4+reg
  float* nump = num_ws + (size_t)s * NEVT * DIM;
#pragma unroll
  for (int mt = 0; mt < 4; ++mt) {
#pragma unroll
    for (int rg = 0; rg < 4; ++rg) {
      int rl = mt * 16 + q * 4 + rg;
      nump[(size_t)(mb * BM + rl) * DIM + wave * 16 + m] = acc[mt][rg];
    }
  }
}

// ---- kernel 4: combine partials + epilogue ----
__global__ void combine_kernel(const float* __restrict__ event,
                               const float* __restrict__ num_ws,
                               const float* __restrict__ den_ws,
                               float* __restrict__ out) {
  int gid = blockIdx.x * 256 + threadIdx.x;
  int base = gid * 4;
  int row = base >> 7;
  int col = base & 127;
  float4v n = {0.f, 0.f, 0.f, 0.f};
  float den = 0.f;
#pragma unroll
  for (int s = 0; s < SPLIT; ++s) {
    float4v v = *(const float4v*)(num_ws + ((size_t)s * NEVT + row) * DIM + col);
    n = n + v;
    den += den_ws[(size_t)s * NEVT + row];
  }
  float4v ev = *(const float4v*)(event + (size_t)row * DIM + col);
  float rdn = 1.0f / den;
  float4v o;
#pragma unroll
  for (int c = 0; c < 4; ++c) o[c] = (ev[c] + n[c] * rdn) * 0.5f;
  *(float4v*)(out + (size_t)row * DIM + col) = o;
}

extern "C" void kernel_launch(void* const* d_in, const int* in_sizes, int n_in,
                              void* d_out, int out_size, void* d_ws,
                              size_t ws_size, hipStream_t stream) {
  const float* adj = (const float*)d_in[0];       // [8192][16384]
  const float* subevent = (const float*)d_in[1];  // [16384][128]
  const float* event = (const float*)d_in[2];     // [8192][128]
  const float* attn_w = (const float*)d_in[3];    // [256]
  float* out = (float*)d_out;                     // [8192][128] fp32

  // ws layout: subfrag (4 MB) | eproj (32 KB) | sproj (64 KB) |
  //            num_ws (16 MB) | den_ws (128 KB)
  char* w = (char*)d_ws;
  unsigned short* subfrag = (unsigned short*)w;
  w += (size_t)NSEVT * DIM * 2;
  float* eproj = (float*)w;
  w += (size_t)NEVT * 4;
  float* sproj = (float*)w;
  w += (size_t)NSEVT * 4;
  float* num_ws = (float*)w;
  w += (size_t)SPLIT * NEVT * DIM * 4;
  float* den_ws = (float*)w;

  proj_kernel<<<(NEVT + NSEVT) / 4, 256, 0, stream>>>(event, subevent, attn_w,
                                                      eproj, sproj);
  frag_kernel<<<(NSEVT / 32) * 8 * 64 / 256, 256, 0, stream>>>(subevent,
                                                               subfrag);
  fused_kernel<<<128 * SPLIT, 512, 0, stream>>>(adj, subfrag, eproj, sproj,
                                                num_ws, den_ws);
  combine_kernel<<<NEVT * DIM / 4 / 256, 256, 0, stream>>>(event, num_ws,
                                                           den_ws, out);
}